// Round 8
// baseline (222.408 us; speedup 1.0000x reference)
//
#include <hip/hip_runtime.h>
#include <stdint.h>

// Problem dims (fixed by the reference)
#define NB   8192
#define NZ   10
#define CIN  512
#define COUT 512
#define MM   3
#define ALPHA 0.04419417382415922f   // 1/sqrt(512)

#define ROWS_TOTAL (NB * MM)          // 24576 GEMM rows (pos,d), d fastest
#define BM 128
#define BN 128
#define BK 32
#define KITERS (CIN / BK)             // 16
#define MAX_MT (ROWS_TOTAL / BM + NZ) // 202
#define NGRP 32                       // decode groups of 256 nodes
#define PW_BLOCKS 320                 // pack-W blocks
#define PT_BLOCKS 2048                // pack-t blocks (4 nodes each)

typedef short bf16x8 __attribute__((ext_vector_type(8)));
typedef float f32x4  __attribute__((ext_vector_type(4)));
typedef uint32_t u32x4 __attribute__((ext_vector_type(4)));   // NT-legal uint4

__device__ __forceinline__ uint16_t f2bf(float f) {
    union { float f; uint32_t i; } v; v.f = f;
    uint32_t x = v.i;
    x += 0x7fffu + ((x >> 16) & 1u);   // RNE
    return (uint16_t)(x >> 16);
}
__device__ __forceinline__ uint32_t pack2(float a, float b) {
    return (uint32_t)f2bf(a) | ((uint32_t)f2bf(b) << 16);
}
__device__ __forceinline__ void async16(const ushort* g, ushort* l) {
    __builtin_amdgcn_global_load_lds((const uint32_t*)g, (uint32_t*)l, 16, 0, 0);
}

// ---- K0: decode(32) + packW(320) + packT(2048) — disjoint block roles ----
__global__ __launch_bounds__(256)
void prep_kernel(const float* __restrict__ t, const float* __restrict__ attrs,
                 const float* __restrict__ w, int* __restrict__ species,
                 int* __restrict__ hist, ushort* __restrict__ wt,
                 ushort* __restrict__ tb) {
    const int tid = threadIdx.x;
    const int wv = tid >> 6, lane = tid & 63;

    if (blockIdx.x < NGRP) {
        // ---- decode one-hot + per-group histogram (ballot, no atomics)
        __shared__ int wc[4][NZ];
        const int b = blockIdx.x * 256 + tid;
        const float* a = attrs + (size_t)b * NZ;
        int s = 0;
        #pragma unroll
        for (int z = 0; z < NZ; z++) if (a[z] > 0.5f) s = z;
        species[b] = s;
        #pragma unroll
        for (int z = 0; z < NZ; z++) {
            unsigned long long m = __ballot(s == z);
            if (lane == 0) wc[wv][z] = __popcll(m);
        }
        __syncthreads();
        if (tid < NZ)
            hist[blockIdx.x * NZ + tid] = wc[0][tid] + wc[1][tid] + wc[2][tid] + wc[3][tid];
    } else if (blockIdx.x < NGRP + PW_BLOCKS) {
        // ---- pack W fp32->bf16 (NT both ways; streamed once)
        const size_t base = (size_t)(blockIdx.x - NGRP) * 8192;
        #pragma unroll
        for (int e = 0; e < 4; e++) {
            const size_t i = base + ((size_t)e * 256 + tid) * 8;
            f32x4 a = __builtin_nontemporal_load((const f32x4*)(w + i));
            f32x4 b = __builtin_nontemporal_load((const f32x4*)(w + i) + 1);
            u32x4 o;
            o.x = pack2(a.x, a.y); o.y = pack2(a.z, a.w);
            o.z = pack2(b.x, b.y); o.w = pack2(b.z, b.w);
            __builtin_nontemporal_store(o, (u32x4*)(wt + i));
        }
    } else {
        // ---- pack t fp32->bf16, ORIGINAL node order, d-major rows:
        // tb[(node*3+d)*CIN + c] = bf16(t[node][c][d]); one wave per node.
        const int p = (blockIdx.x - NGRP - PW_BLOCKS) * 4 + wv;
        const f32x4* src = (const f32x4*)(t + (size_t)p * (CIN * MM) + lane * 24);
        f32x4 f[6];
        #pragma unroll
        for (int i = 0; i < 6; i++) f[i] = __builtin_nontemporal_load(src + i);
        const float* v = (const float*)f;      // v[c_local*3 + d], c_local<8
        #pragma unroll
        for (int d = 0; d < MM; d++) {
            u32x4 o;
            o.x = pack2(v[d],      v[3 + d]);
            o.y = pack2(v[6 + d],  v[9 + d]);
            o.z = pack2(v[12 + d], v[15 + d]);
            o.w = pack2(v[18 + d], v[21 + d]);
            __builtin_nontemporal_store(
                o, (u32x4*)&tb[(size_t)(3 * p + d) * CIN + lane * 8]);
        }
    }
}

// ---- K1: place (deterministic, atomic-free). 32 blocks x 256. ----
__global__ __launch_bounds__(256)
void place_kernel(const int* __restrict__ species, const int* __restrict__ hist,
                  int* __restrict__ sorted, int* __restrict__ offsets,
                  int* __restrict__ tile_offsets) {
    __shared__ int lhist[NGRP][NZ];
    __shared__ int loff[NZ + 1], ltoff[NZ + 1];
    __shared__ int pb[NZ];
    __shared__ int wc[4][NZ];
    const int tid = threadIdx.x, g = blockIdx.x;

    for (int i = tid; i < NGRP * NZ; i += 256) ((int*)lhist)[i] = hist[i];
    __syncthreads();
    if (tid == 0) {
        int off = 0, toff = 0;
        for (int z = 0; z < NZ; z++) {
            int tot = 0;
            for (int gg = 0; gg < NGRP; gg++) tot += lhist[gg][z];
            loff[z] = off; ltoff[z] = toff;
            off += tot;
            toff += (3 * tot + BM - 1) / BM;
        }
        loff[NZ] = off; ltoff[NZ] = toff;
    }
    __syncthreads();
    if (tid < NZ) {
        int base = loff[tid];
        for (int gg = 0; gg < g; gg++) base += lhist[gg][tid];
        pb[tid] = base;
    }
    if (g == 0 && tid < NZ + 1) {
        offsets[tid] = loff[tid];
        tile_offsets[tid] = ltoff[tid];
    }
    const int b = g * 256 + tid;
    const int s = species[b];
    const int wv = tid >> 6, lane = tid & 63;
    unsigned long long mymask = 0;
    #pragma unroll
    for (int z = 0; z < NZ; z++) {
        unsigned long long m = __ballot(s == z);
        if (lane == 0) wc[wv][z] = __popcll(m);
        if (s == z) mymask = m;
    }
    __syncthreads();
    int rank = __popcll(mymask & ((1ull << lane) - 1ull));
    #pragma unroll
    for (int w2 = 0; w2 < 4; w2++) if (w2 < wv) rank += wc[w2][s];
    sorted[pb[s] + rank] = b;
}

// ---- K2: 128x128 MFMA GEMM, A gathered through sorted[] -------------------
__global__ __launch_bounds__(256)
void gemm_kernel(const ushort* __restrict__ tb, const ushort* __restrict__ wt,
                 const int* __restrict__ sorted, const int* __restrict__ offsets,
                 const int* __restrict__ tile_offsets, float* __restrict__ out) {
    __shared__ ushort As[BM][BK];   // 8 KB (global_load_lds layout, no pad)
    __shared__ ushort Bs[BN][BK];   // 8 KB
    __shared__ int spos[48];

    const int mt = blockIdx.x;
    if (mt >= tile_offsets[NZ]) return;          // uniform exit before barriers
    int z = 0;
    #pragma unroll
    for (int i = 1; i < NZ; i++) if (tile_offsets[i] <= mt) z = i;

    const int row_base = 3 * offsets[z] + (mt - tile_offsets[z]) * BM;
    const int row_end  = 3 * offsets[z + 1];
    const int pos0     = row_base / 3;
    const int Cbase    = blockIdx.y * BN;

    const int tid = threadIdx.x;
    const int wv = tid >> 6, lane = tid & 63;

    if (tid < 48) spos[tid] = sorted[min(pos0 + tid, NB - 1)];

    // A-staging: per-lane GATHER via sorted[] (global side per-lane is fine;
    // LDS side is wave-uniform base + lane*16 as required).
    const int lrow = lane >> 2;            // 0..15
    const int lk   = (lane & 3) * 8;
    const int r0 = min(row_base + wv * 32 + lrow,      row_end - 1);
    const int r1 = min(row_base + wv * 32 + 16 + lrow, row_end - 1);
    const int p0 = r0 / 3, d0 = r0 - 3 * p0;
    const int p1 = r1 / 3, d1 = r1 - 3 * p1;
    const ushort* gA0 = tb + ((size_t)sorted[p0] * 3 + d0) * CIN + lk;
    const ushort* gA1 = tb + ((size_t)sorted[p1] * 3 + d1) * CIN + lk;
    const ushort* gB0 = wt + ((size_t)z * COUT + Cbase + wv * 32 + lrow) * CIN + lk;
    const ushort* gB1 = gB0 + (size_t)16 * CIN;
    ushort* lA0 = &As[wv * 32][0];
    ushort* lA1 = &As[wv * 32 + 16][0];
    ushort* lB0 = &Bs[wv * 32][0];
    ushort* lB1 = &Bs[wv * 32 + 16][0];

    const int wm = wv & 1, wn = wv >> 1;
    const int q = lane >> 4, mr = lane & 15;

    f32x4 acc[4][4];
    #pragma unroll
    for (int i = 0; i < 4; i++)
        #pragma unroll
        for (int j = 0; j < 4; j++) acc[i][j] = (f32x4){0.f, 0.f, 0.f, 0.f};

    for (int kt = 0; kt < KITERS; kt++) {
        const int ko = kt * BK;
        async16(gA0 + ko, lA0);
        async16(gA1 + ko, lA1);
        async16(gB0 + ko, lB0);
        async16(gB1 + ko, lB1);
        __syncthreads();

        bf16x8 af[4], bf[4];
        #pragma unroll
        for (int am = 0; am < 4; am++)
            af[am] = *(const bf16x8*)&As[wm * 64 + am * 16 + mr][q * 8];
        #pragma unroll
        for (int bn = 0; bn < 4; bn++)
            bf[bn] = *(const bf16x8*)&Bs[wn * 64 + bn * 16 + mr][q * 8];
        #pragma unroll
        for (int am = 0; am < 4; am++)
            #pragma unroll
            for (int bn = 0; bn < 4; bn++)
                acc[am][bn] = __builtin_amdgcn_mfma_f32_16x16x32_bf16(
                    af[am], bf[bn], acc[am][bn], 0, 0, 0);
        __syncthreads();
    }

    // epilogue: row -> (pos,d); out[node][C][d], NT stores (never re-read)
    #pragma unroll
    for (int am = 0; am < 4; am++) {
        #pragma unroll
        for (int r = 0; r < 4; r++) {
            const int Rg = row_base + wm * 64 + am * 16 + q * 4 + r;
            if (Rg < row_end) {
                const int pos = Rg / 3;
                const int d = Rg - 3 * pos;
                const int node = spos[pos - pos0];
                float* o = out + (size_t)node * (COUT * MM) + d;
                #pragma unroll
                for (int bn = 0; bn < 4; bn++) {
                    const int Cg = Cbase + wn * 64 + bn * 16 + mr;
                    __builtin_nontemporal_store(ALPHA * acc[am][bn][r],
                                                o + (size_t)Cg * 3);
                }
            }
        }
    }
}

extern "C" void kernel_launch(void* const* d_in, const int* in_sizes, int n_in,
                              void* d_out, int out_size, void* d_ws, size_t ws_size,
                              hipStream_t stream) {
    const float* t     = (const float*)d_in[0];   // [B, IN, 3]  fp32
    const float* attrs = (const float*)d_in[1];   // [B, Z]      fp32 one-hot
    const float* w     = (const float*)d_in[2];   // [Z, OUT, IN] fp32
    float* out = (float*)d_out;                   // [B, OUT, 3] fp32

    uint8_t* ws = (uint8_t*)d_ws;
    int* species      = (int*)ws;                  ws += NB * 4;
    int* sorted       = (int*)ws;                  ws += NB * 4;
    int* hist         = (int*)ws;                  ws += NGRP * NZ * 4;
    int* offsets      = (int*)ws;                  ws += 16 * 4;
    int* tile_offsets = (int*)ws;                  ws += 16 * 4;
    ws = (uint8_t*)(((uintptr_t)ws + 255) & ~(uintptr_t)255);
    ushort* wt = (ushort*)ws;                      ws += (size_t)NZ * COUT * CIN * 2;
    ushort* tb = (ushort*)ws;                      // ROWS_TOTAL x CIN bf16

    hipLaunchKernelGGL(prep_kernel, dim3(NGRP + PW_BLOCKS + PT_BLOCKS), dim3(256),
                       0, stream, t, attrs, w, species, hist, wt, tb);
    hipLaunchKernelGGL(place_kernel, dim3(NGRP), dim3(256), 0, stream,
                       species, hist, sorted, offsets, tile_offsets);
    hipLaunchKernelGGL(gemm_kernel, dim3(MAX_MT, COUT / BN), dim3(256), 0, stream,
                       tb, wt, sorted, offsets, tile_offsets, out);
}

// Round 9
// 167.177 us; speedup vs baseline: 1.3304x; 1.3304x over previous
//
#include <hip/hip_runtime.h>
#include <stdint.h>

// Problem dims (fixed by the reference)
#define NB   8192
#define NZ   10
#define CIN  512
#define COUT 512
#define MM   3
#define ALPHA 0.04419417382415922f   // 1/sqrt(512)

#define ROWS_TOTAL (NB * MM)          // 24576 GEMM rows (pos,d), d fastest
#define BM 128
#define BN 128
#define BK 32
#define KITERS (CIN / BK)             // 16
#define MAX_MT (ROWS_TOTAL / BM + NZ) // 202
#define NGRP 32                       // decode groups of 256 nodes
#define PW_BLOCKS 320                 // pack-W blocks
#define PT_BLOCKS 2048                // pack-t blocks (4 nodes each)

typedef short bf16x8 __attribute__((ext_vector_type(8)));
typedef float f32x4  __attribute__((ext_vector_type(4)));
typedef uint32_t u32x4 __attribute__((ext_vector_type(4)));

__device__ __forceinline__ uint16_t f2bf(float f) {
    union { float f; uint32_t i; } v; v.f = f;
    uint32_t x = v.i;
    x += 0x7fffu + ((x >> 16) & 1u);   // RNE
    return (uint16_t)(x >> 16);
}
__device__ __forceinline__ uint32_t pack2(float a, float b) {
    return (uint32_t)f2bf(a) | ((uint32_t)f2bf(b) << 16);
}
__device__ __forceinline__ void async16(const ushort* g, ushort* l) {
    __builtin_amdgcn_global_load_lds((const uint32_t*)g, (uint32_t*)l, 16, 0, 0);
}

// ---- K0: decode(32) + packW(320) + packT(2048) — disjoint block roles ----
// NT loads only (t/w are read-once streams; keep L2 clean for tb/wt).
// Stores are REGULAR: tb/wt are re-read by the gemm, and NT scalar/partial
// stores caused 3.4x HBM write amplification in R8.
__global__ __launch_bounds__(256)
void prep_kernel(const float* __restrict__ t, const float* __restrict__ attrs,
                 const float* __restrict__ w, int* __restrict__ species,
                 int* __restrict__ hist, ushort* __restrict__ wt,
                 ushort* __restrict__ tb) {
    const int tid = threadIdx.x;
    const int wv = tid >> 6, lane = tid & 63;

    if (blockIdx.x < NGRP) {
        // ---- decode one-hot + per-group histogram (ballot, no atomics)
        __shared__ int wc[4][NZ];
        const int b = blockIdx.x * 256 + tid;
        const float* a = attrs + (size_t)b * NZ;
        int s = 0;
        #pragma unroll
        for (int z = 0; z < NZ; z++) if (a[z] > 0.5f) s = z;
        species[b] = s;
        #pragma unroll
        for (int z = 0; z < NZ; z++) {
            unsigned long long m = __ballot(s == z);
            if (lane == 0) wc[wv][z] = __popcll(m);
        }
        __syncthreads();
        if (tid < NZ)
            hist[blockIdx.x * NZ + tid] = wc[0][tid] + wc[1][tid] + wc[2][tid] + wc[3][tid];
    } else if (blockIdx.x < NGRP + PW_BLOCKS) {
        // ---- pack W fp32->bf16
        const size_t base = (size_t)(blockIdx.x - NGRP) * 8192;
        #pragma unroll
        for (int e = 0; e < 4; e++) {
            const size_t i = base + ((size_t)e * 256 + tid) * 8;
            f32x4 a = __builtin_nontemporal_load((const f32x4*)(w + i));
            f32x4 b = __builtin_nontemporal_load((const f32x4*)(w + i) + 1);
            u32x4 o;
            o.x = pack2(a.x, a.y); o.y = pack2(a.z, a.w);
            o.z = pack2(b.x, b.y); o.w = pack2(b.z, b.w);
            *(u32x4*)(wt + i) = o;
        }
    } else {
        // ---- pack t fp32->bf16, ORIGINAL node order, d-major rows:
        // tb[(node*3+d)*CIN + c] = bf16(t[node][c][d]); one wave per node.
        const int p = (blockIdx.x - NGRP - PW_BLOCKS) * 4 + wv;
        const f32x4* src = (const f32x4*)(t + (size_t)p * (CIN * MM) + lane * 24);
        f32x4 f[6];
        #pragma unroll
        for (int i = 0; i < 6; i++) f[i] = __builtin_nontemporal_load(src + i);
        const float* v = (const float*)f;      // v[c_local*3 + d], c_local<8
        #pragma unroll
        for (int d = 0; d < MM; d++) {
            u32x4 o;
            o.x = pack2(v[d],      v[3 + d]);
            o.y = pack2(v[6 + d],  v[9 + d]);
            o.z = pack2(v[12 + d], v[15 + d]);
            o.w = pack2(v[18 + d], v[21 + d]);
            *(u32x4*)&tb[(size_t)(3 * p + d) * CIN + lane * 8] = o;
        }
    }
}

// ---- K1: place (deterministic, atomic-free). 32 blocks x 256. ----
__global__ __launch_bounds__(256)
void place_kernel(const int* __restrict__ species, const int* __restrict__ hist,
                  int* __restrict__ sorted, int* __restrict__ offsets,
                  int* __restrict__ tile_offsets) {
    __shared__ int lhist[NGRP][NZ];
    __shared__ int loff[NZ + 1], ltoff[NZ + 1];
    __shared__ int pb[NZ];
    __shared__ int wc[4][NZ];
    const int tid = threadIdx.x, g = blockIdx.x;

    for (int i = tid; i < NGRP * NZ; i += 256) ((int*)lhist)[i] = hist[i];
    __syncthreads();
    if (tid == 0) {
        int off = 0, toff = 0;
        for (int z = 0; z < NZ; z++) {
            int tot = 0;
            for (int gg = 0; gg < NGRP; gg++) tot += lhist[gg][z];
            loff[z] = off; ltoff[z] = toff;
            off += tot;
            toff += (3 * tot + BM - 1) / BM;
        }
        loff[NZ] = off; ltoff[NZ] = toff;
    }
    __syncthreads();
    if (tid < NZ) {
        int base = loff[tid];
        for (int gg = 0; gg < g; gg++) base += lhist[gg][tid];
        pb[tid] = base;
    }
    if (g == 0 && tid < NZ + 1) {
        offsets[tid] = loff[tid];
        tile_offsets[tid] = ltoff[tid];
    }
    const int b = g * 256 + tid;
    const int s = species[b];
    const int wv = tid >> 6, lane = tid & 63;
    unsigned long long mymask = 0;
    #pragma unroll
    for (int z = 0; z < NZ; z++) {
        unsigned long long m = __ballot(s == z);
        if (lane == 0) wc[wv][z] = __popcll(m);
        if (s == z) mymask = m;
    }
    __syncthreads();
    int rank = __popcll(mymask & ((1ull << lane) - 1ull));
    #pragma unroll
    for (int w2 = 0; w2 < 4; w2++) if (w2 < wv) rank += wc[w2][s];
    sorted[pb[s] + rank] = b;
}

// ---- K2: 128x128 MFMA GEMM, A gathered through sorted[] -------------------
__global__ __launch_bounds__(256)
void gemm_kernel(const ushort* __restrict__ tb, const ushort* __restrict__ wt,
                 const int* __restrict__ sorted, const int* __restrict__ offsets,
                 const int* __restrict__ tile_offsets, float* __restrict__ out) {
    __shared__ ushort As[BM][BK];   // 8 KB (global_load_lds layout, no pad)
    __shared__ ushort Bs[BN][BK];   // 8 KB
    __shared__ int spos[48];

    const int mt = blockIdx.x;
    if (mt >= tile_offsets[NZ]) return;          // uniform exit before barriers
    int z = 0;
    #pragma unroll
    for (int i = 1; i < NZ; i++) if (tile_offsets[i] <= mt) z = i;

    const int row_base = 3 * offsets[z] + (mt - tile_offsets[z]) * BM;
    const int row_end  = 3 * offsets[z + 1];
    const int pos0     = row_base / 3;
    const int Cbase    = blockIdx.y * BN;

    const int tid = threadIdx.x;
    const int wv = tid >> 6, lane = tid & 63;

    if (tid < 48) spos[tid] = sorted[min(pos0 + tid, NB - 1)];

    // A-staging: per-lane GATHER via sorted[] (global side per-lane is fine;
    // LDS side is wave-uniform base + lane*16 as required).
    const int lrow = lane >> 2;            // 0..15
    const int lk   = (lane & 3) * 8;
    const int r0 = min(row_base + wv * 32 + lrow,      row_end - 1);
    const int r1 = min(row_base + wv * 32 + 16 + lrow, row_end - 1);
    const int p0 = r0 / 3, d0 = r0 - 3 * p0;
    const int p1 = r1 / 3, d1 = r1 - 3 * p1;
    const ushort* gA0 = tb + ((size_t)sorted[p0] * 3 + d0) * CIN + lk;
    const ushort* gA1 = tb + ((size_t)sorted[p1] * 3 + d1) * CIN + lk;
    const ushort* gB0 = wt + ((size_t)z * COUT + Cbase + wv * 32 + lrow) * CIN + lk;
    const ushort* gB1 = gB0 + (size_t)16 * CIN;
    ushort* lA0 = &As[wv * 32][0];
    ushort* lA1 = &As[wv * 32 + 16][0];
    ushort* lB0 = &Bs[wv * 32][0];
    ushort* lB1 = &Bs[wv * 32 + 16][0];

    const int wm = wv & 1, wn = wv >> 1;
    const int q = lane >> 4, mr = lane & 15;

    f32x4 acc[4][4];
    #pragma unroll
    for (int i = 0; i < 4; i++)
        #pragma unroll
        for (int j = 0; j < 4; j++) acc[i][j] = (f32x4){0.f, 0.f, 0.f, 0.f};

    for (int kt = 0; kt < KITERS; kt++) {
        const int ko = kt * BK;
        async16(gA0 + ko, lA0);
        async16(gA1 + ko, lA1);
        async16(gB0 + ko, lB0);
        async16(gB1 + ko, lB1);
        __syncthreads();

        bf16x8 af[4], bf[4];
        #pragma unroll
        for (int am = 0; am < 4; am++)
            af[am] = *(const bf16x8*)&As[wm * 64 + am * 16 + mr][q * 8];
        #pragma unroll
        for (int bn = 0; bn < 4; bn++)
            bf[bn] = *(const bf16x8*)&Bs[wn * 64 + bn * 16 + mr][q * 8];
        #pragma unroll
        for (int am = 0; am < 4; am++)
            #pragma unroll
            for (int bn = 0; bn < 4; bn++)
                acc[am][bn] = __builtin_amdgcn_mfma_f32_16x16x32_bf16(
                    af[am], bf[bn], acc[am][bn], 0, 0, 0);
        __syncthreads();
    }

    // epilogue: row -> (pos,d); out[node][C][d]; PLAIN stores (R8's NT scalar
    // stores caused 3.4x HBM write amplification: 57->168 MB, +55 us)
    #pragma unroll
    for (int am = 0; am < 4; am++) {
        #pragma unroll
        for (int r = 0; r < 4; r++) {
            const int Rg = row_base + wm * 64 + am * 16 + q * 4 + r;
            if (Rg < row_end) {
                const int pos = Rg / 3;
                const int d = Rg - 3 * pos;
                const int node = spos[pos - pos0];
                float* o = out + (size_t)node * (COUT * MM) + d;
                #pragma unroll
                for (int bn = 0; bn < 4; bn++) {
                    const int Cg = Cbase + wn * 64 + bn * 16 + mr;
                    o[(size_t)Cg * 3] = ALPHA * acc[am][bn][r];
                }
            }
        }
    }
}

extern "C" void kernel_launch(void* const* d_in, const int* in_sizes, int n_in,
                              void* d_out, int out_size, void* d_ws, size_t ws_size,
                              hipStream_t stream) {
    const float* t     = (const float*)d_in[0];   // [B, IN, 3]  fp32
    const float* attrs = (const float*)d_in[1];   // [B, Z]      fp32 one-hot
    const float* w     = (const float*)d_in[2];   // [Z, OUT, IN] fp32
    float* out = (float*)d_out;                   // [B, OUT, 3] fp32

    uint8_t* ws = (uint8_t*)d_ws;
    int* species      = (int*)ws;                  ws += NB * 4;
    int* sorted       = (int*)ws;                  ws += NB * 4;
    int* hist         = (int*)ws;                  ws += NGRP * NZ * 4;
    int* offsets      = (int*)ws;                  ws += 16 * 4;
    int* tile_offsets = (int*)ws;                  ws += 16 * 4;
    ws = (uint8_t*)(((uintptr_t)ws + 255) & ~(uintptr_t)255);
    ushort* wt = (ushort*)ws;                      ws += (size_t)NZ * COUT * CIN * 2;
    ushort* tb = (ushort*)ws;                      // ROWS_TOTAL x CIN bf16

    hipLaunchKernelGGL(prep_kernel, dim3(NGRP + PW_BLOCKS + PT_BLOCKS), dim3(256),
                       0, stream, t, attrs, w, species, hist, wt, tb);
    hipLaunchKernelGGL(place_kernel, dim3(NGRP), dim3(256), 0, stream,
                       species, hist, sorted, offsets, tile_offsets);
    hipLaunchKernelGGL(gemm_kernel, dim3(MAX_MT, COUT / BN), dim3(256), 0, stream,
                       tb, wt, sorted, offsets, tile_offsets, out);
}

// Round 10
// 161.049 us; speedup vs baseline: 1.3810x; 1.0380x over previous
//
#include <hip/hip_runtime.h>
#include <stdint.h>

// Problem dims (fixed by the reference)
#define NB   8192
#define NZ   10
#define CIN  512
#define COUT 512
#define MM   3
#define ALPHA 0.04419417382415922f   // 1/sqrt(512)

#define ROWS_TOTAL (NB * MM)          // 24576 GEMM rows (pos,d), d fastest
#define BM 128
#define BN 128
#define BK 64
#define KITERS (CIN / BK)             // 8
#define MAX_MT (ROWS_TOTAL / BM + NZ) // 202
#define NGRP 32                       // decode groups of 256 nodes
#define PW_BLOCKS 320                 // pack-W blocks
#define PT_BLOCKS 2048                // pack-t blocks (4 nodes each)

typedef short bf16x8 __attribute__((ext_vector_type(8)));
typedef float f32x4  __attribute__((ext_vector_type(4)));
typedef uint32_t u32x4 __attribute__((ext_vector_type(4)));

__device__ __forceinline__ uint16_t f2bf(float f) {
    union { float f; uint32_t i; } v; v.f = f;
    uint32_t x = v.i;
    x += 0x7fffu + ((x >> 16) & 1u);   // RNE
    return (uint16_t)(x >> 16);
}
__device__ __forceinline__ uint32_t pack2(float a, float b) {
    return (uint32_t)f2bf(a) | ((uint32_t)f2bf(b) << 16);
}
__device__ __forceinline__ void async16(const ushort* g, ushort* l) {
    __builtin_amdgcn_global_load_lds((const uint32_t*)g, (uint32_t*)l, 16, 0, 0);
}

// ---- K0: decode(32) + packW(320) + packT(2048) — disjoint block roles ----
__global__ __launch_bounds__(256)
void prep_kernel(const float* __restrict__ t, const float* __restrict__ attrs,
                 const float* __restrict__ w, int* __restrict__ species,
                 int* __restrict__ hist, ushort* __restrict__ wt,
                 ushort* __restrict__ tb) {
    const int tid = threadIdx.x;
    const int wv = tid >> 6, lane = tid & 63;

    if (blockIdx.x < NGRP) {
        // ---- decode one-hot + per-group histogram (ballot, no atomics)
        __shared__ int wc[4][NZ];
        const int b = blockIdx.x * 256 + tid;
        const float* a = attrs + (size_t)b * NZ;
        int s = 0;
        #pragma unroll
        for (int z = 0; z < NZ; z++) if (a[z] > 0.5f) s = z;
        species[b] = s;
        #pragma unroll
        for (int z = 0; z < NZ; z++) {
            unsigned long long m = __ballot(s == z);
            if (lane == 0) wc[wv][z] = __popcll(m);
        }
        __syncthreads();
        if (tid < NZ)
            hist[blockIdx.x * NZ + tid] = wc[0][tid] + wc[1][tid] + wc[2][tid] + wc[3][tid];
    } else if (blockIdx.x < NGRP + PW_BLOCKS) {
        // ---- pack W fp32->bf16 (NT loads; regular stores — re-read by gemm)
        const size_t base = (size_t)(blockIdx.x - NGRP) * 8192;
        #pragma unroll
        for (int e = 0; e < 4; e++) {
            const size_t i = base + ((size_t)e * 256 + tid) * 8;
            f32x4 a = __builtin_nontemporal_load((const f32x4*)(w + i));
            f32x4 b = __builtin_nontemporal_load((const f32x4*)(w + i) + 1);
            u32x4 o;
            o.x = pack2(a.x, a.y); o.y = pack2(a.z, a.w);
            o.z = pack2(b.x, b.y); o.w = pack2(b.z, b.w);
            *(u32x4*)(wt + i) = o;
        }
    } else {
        // ---- pack t fp32->bf16, ORIGINAL node order, d-major rows:
        // tb[(node*3+d)*CIN + c] = bf16(t[node][c][d]); one wave per node.
        const int p = (blockIdx.x - NGRP - PW_BLOCKS) * 4 + wv;
        const f32x4* src = (const f32x4*)(t + (size_t)p * (CIN * MM) + lane * 24);
        f32x4 f[6];
        #pragma unroll
        for (int i = 0; i < 6; i++) f[i] = __builtin_nontemporal_load(src + i);
        const float* v = (const float*)f;      // v[c_local*3 + d], c_local<8
        #pragma unroll
        for (int d = 0; d < MM; d++) {
            u32x4 o;
            o.x = pack2(v[d],      v[3 + d]);
            o.y = pack2(v[6 + d],  v[9 + d]);
            o.z = pack2(v[12 + d], v[15 + d]);
            o.w = pack2(v[18 + d], v[21 + d]);
            *(u32x4*)&tb[(size_t)(3 * p + d) * CIN + lane * 8] = o;
        }
    }
}

// ---- K1: place (deterministic, atomic-free). 32 blocks x 256. ----
__global__ __launch_bounds__(256)
void place_kernel(const int* __restrict__ species, const int* __restrict__ hist,
                  int* __restrict__ sorted, int* __restrict__ offsets,
                  int* __restrict__ tile_offsets) {
    __shared__ int lhist[NGRP][NZ];
    __shared__ int loff[NZ + 1], ltoff[NZ + 1];
    __shared__ int pb[NZ];
    __shared__ int wc[4][NZ];
    const int tid = threadIdx.x, g = blockIdx.x;

    for (int i = tid; i < NGRP * NZ; i += 256) ((int*)lhist)[i] = hist[i];
    __syncthreads();
    if (tid == 0) {
        int off = 0, toff = 0;
        for (int z = 0; z < NZ; z++) {
            int tot = 0;
            for (int gg = 0; gg < NGRP; gg++) tot += lhist[gg][z];
            loff[z] = off; ltoff[z] = toff;
            off += tot;
            toff += (3 * tot + BM - 1) / BM;
        }
        loff[NZ] = off; ltoff[NZ] = toff;
    }
    __syncthreads();
    if (tid < NZ) {
        int base = loff[tid];
        for (int gg = 0; gg < g; gg++) base += lhist[gg][tid];
        pb[tid] = base;
    }
    if (g == 0 && tid < NZ + 1) {
        offsets[tid] = loff[tid];
        tile_offsets[tid] = ltoff[tid];
    }
    const int b = g * 256 + tid;
    const int s = species[b];
    const int wv = tid >> 6, lane = tid & 63;
    unsigned long long mymask = 0;
    #pragma unroll
    for (int z = 0; z < NZ; z++) {
        unsigned long long m = __ballot(s == z);
        if (lane == 0) wc[wv][z] = __popcll(m);
        if (s == z) mymask = m;
    }
    __syncthreads();
    int rank = __popcll(mymask & ((1ull << lane) - 1ull));
    #pragma unroll
    for (int w2 = 0; w2 < 4; w2++) if (w2 < wv) rank += wc[w2][s];
    sorted[pb[s] + rank] = b;
}

// ---- K2: 128x128xBK64 MFMA GEMM, XOR-swizzled LDS, gather-A ---------------
// LDS physical chunk c (16B) of row r holds global k-chunk c^(r&7): the
// global_load_lds source address is permuted per-lane, so fragment reads at
// chunk (s*4+q)^(mr&7) are bank-conflict-free (2 lanes/bank = free).
__global__ __launch_bounds__(256)
void gemm_kernel(const ushort* __restrict__ tb, const ushort* __restrict__ wt,
                 const int* __restrict__ sorted, const int* __restrict__ offsets,
                 const int* __restrict__ tile_offsets, float* __restrict__ out) {
    __shared__ ushort As[BM][BK];   // 16 KB
    __shared__ ushort Bs[BN][BK];   // 16 KB
    __shared__ int spos[48];

    const int mt = blockIdx.y;                    // nt is the FAST grid dim:
    const int Cbase = blockIdx.x * BN;            // 4 sibling blocks share A
    if (mt >= tile_offsets[NZ]) return;           // uniform exit before barriers
    int z = 0;
    #pragma unroll
    for (int i = 1; i < NZ; i++) if (tile_offsets[i] <= mt) z = i;

    const int row_base = 3 * offsets[z] + (mt - tile_offsets[z]) * BM;
    const int row_end  = 3 * offsets[z + 1];
    const int pos0     = row_base / 3;

    const int tid = threadIdx.x;
    const int wv = tid >> 6, lane = tid & 63;

    if (tid < 48) spos[tid] = sorted[min(pos0 + tid, NB - 1)];

    // staging roles: per async16, 64 lanes cover 8 rows x 8 chunks (1 KB)
    const int sub = lane >> 3;                 // row within 8-row group
    const int kc  = (lane & 7) ^ sub;          // swizzled global k-chunk
    const ushort* gA[4];
    #pragma unroll
    for (int j = 0; j < 4; j++) {
        const int r = min(row_base + wv * 32 + j * 8 + sub, row_end - 1);
        const int p = r / 3, d = r - 3 * p;
        gA[j] = tb + ((size_t)sorted[p] * 3 + d) * CIN + kc * 8;
    }
    const ushort* gB = wt + ((size_t)z * COUT + Cbase + wv * 32 + sub) * CIN + kc * 8;

    const int wm = wv & 1, wn = wv >> 1;
    const int q = lane >> 4, mr = lane & 15;

    f32x4 acc[4][4];
    #pragma unroll
    for (int i = 0; i < 4; i++)
        #pragma unroll
        for (int j = 0; j < 4; j++) acc[i][j] = (f32x4){0.f, 0.f, 0.f, 0.f};

    for (int kt = 0; kt < KITERS; kt++) {
        const int ko = kt * BK;
        #pragma unroll
        for (int j = 0; j < 4; j++)
            async16(gA[j] + ko, &As[wv * 32 + j * 8][0]);
        #pragma unroll
        for (int j = 0; j < 4; j++)
            async16(gB + (size_t)(j * 8) * CIN + ko, &Bs[wv * 32 + j * 8][0]);
        __syncthreads();

        #pragma unroll
        for (int s = 0; s < 2; s++) {          // two K=32 steps inside BK=64
            bf16x8 af[4], bf[4];
            #pragma unroll
            for (int am = 0; am < 4; am++) {
                const int ra = wm * 64 + am * 16 + mr;
                af[am] = *(const bf16x8*)&As[ra][((s * 4 + q) ^ (mr & 7)) * 8];
            }
            #pragma unroll
            for (int bn = 0; bn < 4; bn++) {
                const int rb = wn * 64 + bn * 16 + mr;
                bf[bn] = *(const bf16x8*)&Bs[rb][((s * 4 + q) ^ (mr & 7)) * 8];
            }
            #pragma unroll
            for (int am = 0; am < 4; am++)
                #pragma unroll
                for (int bn = 0; bn < 4; bn++)
                    acc[am][bn] = __builtin_amdgcn_mfma_f32_16x16x32_bf16(
                        af[am], bf[bn], acc[am][bn], 0, 0, 0);
        }
        __syncthreads();
    }

    // epilogue: row -> (pos,d); out[node][C][d]; plain stores
    #pragma unroll
    for (int am = 0; am < 4; am++) {
        #pragma unroll
        for (int r = 0; r < 4; r++) {
            const int Rg = row_base + wm * 64 + am * 16 + q * 4 + r;
            if (Rg < row_end) {
                const int pos = Rg / 3;
                const int d = Rg - 3 * pos;
                const int node = spos[pos - pos0];
                float* o = out + (size_t)node * (COUT * MM) + d;
                #pragma unroll
                for (int bn = 0; bn < 4; bn++) {
                    const int Cg = Cbase + wn * 64 + bn * 16 + mr;
                    o[(size_t)Cg * 3] = ALPHA * acc[am][bn][r];
                }
            }
        }
    }
}

extern "C" void kernel_launch(void* const* d_in, const int* in_sizes, int n_in,
                              void* d_out, int out_size, void* d_ws, size_t ws_size,
                              hipStream_t stream) {
    const float* t     = (const float*)d_in[0];   // [B, IN, 3]  fp32
    const float* attrs = (const float*)d_in[1];   // [B, Z]      fp32 one-hot
    const float* w     = (const float*)d_in[2];   // [Z, OUT, IN] fp32
    float* out = (float*)d_out;                   // [B, OUT, 3] fp32

    uint8_t* ws = (uint8_t*)d_ws;
    int* species      = (int*)ws;                  ws += NB * 4;
    int* sorted       = (int*)ws;                  ws += NB * 4;
    int* hist         = (int*)ws;                  ws += NGRP * NZ * 4;
    int* offsets      = (int*)ws;                  ws += 16 * 4;
    int* tile_offsets = (int*)ws;                  ws += 16 * 4;
    ws = (uint8_t*)(((uintptr_t)ws + 255) & ~(uintptr_t)255);
    ushort* wt = (ushort*)ws;                      ws += (size_t)NZ * COUT * CIN * 2;
    ushort* tb = (ushort*)ws;                      // ROWS_TOTAL x CIN bf16

    hipLaunchKernelGGL(prep_kernel, dim3(NGRP + PW_BLOCKS + PT_BLOCKS), dim3(256),
                       0, stream, t, attrs, w, species, hist, wt, tb);
    hipLaunchKernelGGL(place_kernel, dim3(NGRP), dim3(256), 0, stream,
                       species, hist, sorted, offsets, tile_offsets);
    hipLaunchKernelGGL(gemm_kernel, dim3(COUT / BN, MAX_MT), dim3(256), 0, stream,
                       tb, wt, sorted, offsets, tile_offsets, out);
}